// Round 4
// baseline (595.445 us; speedup 1.0000x reference)
//
#include <hip/hip_runtime.h>

// MQA: B=2, S=2048, HID=2048, H=16, D=128 (single KV head), causal.
// Pipeline: cast -> fused QKV NT-GEMM (bf16 MFMA) -> V transpose -> kmax ->
//           flash attention (direct-from-L2 K/V, barrier-free, Cauchy-bound
//           softmax) -> out NT-GEMM.

#define S_LEN 2048
#define HID_  2048
#define D_    128
#define NQKV  2304   // 2048 Q + 128 K + 128 V columns

typedef __attribute__((ext_vector_type(8))) short bf16x8;
typedef __attribute__((ext_vector_type(4))) short s16x4;
typedef __attribute__((ext_vector_type(4))) float f32x4;

__device__ __forceinline__ unsigned short f2b(float f) {
  union { float f; unsigned int u; } a; a.f = f;
  unsigned int u = a.u;
  return (unsigned short)((u + 0x7fffu + ((u >> 16) & 1u)) >> 16);  // RNE
}

__device__ __forceinline__ float b2f(unsigned short s) {
  union { unsigned int u; float f; } a; a.u = ((unsigned int)s) << 16;
  return a.f;
}

__device__ __forceinline__ void load_lds16(const void* g, void* l) {
  __builtin_amdgcn_global_load_lds(
      (const __attribute__((address_space(1))) void*)g,
      (__attribute__((address_space(3))) void*)l, 16, 0, 0);
}

__device__ __forceinline__ f32x4 mfma16(bf16x8 a, bf16x8 b, f32x4 c) {
  return __builtin_amdgcn_mfma_f32_16x16x32_bf16(a, b, c, 0, 0, 0);
}

// ---------------- casts / packing ----------------

__global__ void cast_f32_bf16_k(const float* __restrict__ in,
                                unsigned short* __restrict__ out, int n4) {
  const int idx = blockIdx.x * 256 + threadIdx.x;
  if (idx < n4) {
    const float4 v = ((const float4*)in)[idx];
    ushort4 o;
    o.x = f2b(v.x); o.y = f2b(v.y); o.z = f2b(v.z); o.w = f2b(v.w);
    ((ushort4*)out)[idx] = o;
  }
}

__global__ void build_wcat_k(const float* __restrict__ Wq,
                             const float* __restrict__ Wk,
                             const float* __restrict__ Wv,
                             const float* __restrict__ bq,
                             const float* __restrict__ bk,
                             const float* __restrict__ bv,
                             unsigned short* __restrict__ Wcat,
                             float* __restrict__ bcat,
                             float* __restrict__ Kmax) {
  const int idx = blockIdx.x * 256 + threadIdx.x;
  const int i = idx * 4;
  const int row = i >> 11;
  const int col = i & 2047;
  const float* src;
  if (row < 2048)      src = Wq + (size_t)row * 2048 + col;
  else if (row < 2176) src = Wk + (size_t)(row - 2048) * 2048 + col;
  else                 src = Wv + (size_t)(row - 2176) * 2048 + col;
  const float4 v = *(const float4*)src;
  ushort4 o;
  o.x = f2b(v.x); o.y = f2b(v.y); o.z = f2b(v.z); o.w = f2b(v.w);
  *(ushort4*)(Wcat + i) = o;
  if (idx < NQKV)
    bcat[idx] = (idx < 2048) ? bq[idx] : (idx < 2176) ? bk[idx - 2048] : bv[idx - 2176];
  if (idx < 2) Kmax[idx] = 0.f;   // re-init every launch (runs before kmax_k)
}

// Vt[b][d][s] = QKV[b*S+s][2176+d] -- LDS-tiled transpose
__global__ __launch_bounds__(256)
void transpose_v(const unsigned short* __restrict__ QKV,
                 unsigned short* __restrict__ Vt) {
  __shared__ unsigned short tile[64][136];
  const int tid = threadIdx.x;
  const int s0  = blockIdx.x * 64;
  const int b   = blockIdx.y;
  const int row = tid >> 2;
  const int cb  = (tid & 3) * 32;
  const unsigned short* src = QKV + (size_t)(b * S_LEN + s0 + row) * NQKV + 2176 + cb;
#pragma unroll
  for (int i = 0; i < 4; ++i)
    *(bf16x8*)&tile[row][cb + i * 8] = *(const bf16x8*)(src + i * 8);
  __syncthreads();
  const int d  = tid >> 1;
  const int sc = (tid & 1) * 32;
  unsigned short* dst = Vt + ((size_t)b * D_ + d) * S_LEN + s0 + sc;
#pragma unroll
  for (int i = 0; i < 4; ++i) {
    bf16x8 vv;
#pragma unroll
    for (int e = 0; e < 8; ++e) vv[e] = tile[sc + i * 8 + e][d];
    *(bf16x8*)(dst + i * 8) = vv;
  }
}

// max_s ||k[b,s]||^2 -> Kmax[b] (as float bits via atomicMax on uint)
__global__ __launch_bounds__(256)
void kmax_k(const unsigned short* __restrict__ QKV, float* __restrict__ Kmax) {
  __shared__ float red[256];
  const int tid = threadIdx.x;
  const int b = blockIdx.x >> 3;
  const int s = (blockIdx.x & 7) * 256 + tid;
  const unsigned short* kp = QKV + (size_t)(b * S_LEN + s) * NQKV + 2048;
  float sum = 0.f;
#pragma unroll
  for (int i = 0; i < 16; ++i) {
    bf16x8 v = *(const bf16x8*)(kp + i * 8);
#pragma unroll
    for (int e = 0; e < 8; ++e) { const float f = b2f((unsigned short)v[e]); sum += f * f; }
  }
  red[tid] = sum;
  __syncthreads();
  for (int off = 128; off > 0; off >>= 1) {
    if (tid < off) red[tid] = fmaxf(red[tid], red[tid + off]);
    __syncthreads();
  }
  if (tid == 0) atomicMax((unsigned int*)(Kmax + b), __float_as_uint(red[0]));
}

// ---------------- NT GEMM (m97 structure, unchanged) ----------------

template <int OUT_F32>
__global__ __launch_bounds__(256)
void gemm_nt(const unsigned short* __restrict__ A,
             const unsigned short* __restrict__ Bm,
             const float* __restrict__ bias,
             void* __restrict__ Cv,
             int M, int N, int K) {
  __shared__ unsigned short As[128 * 32];
  __shared__ unsigned short Bs[128 * 32];
  const int tid  = threadIdx.x;
  const int lane = tid & 63;
  const int wv   = tid >> 6;
  const int wr   = wv >> 1, wc = wv & 1;
  const int g    = lane >> 4, r = lane & 15;
  const int m0   = blockIdx.y * 128;
  const int n0   = blockIdx.x * 128;

  const unsigned short* ga0 = A  + (size_t)(m0 + (tid >> 2)) * K + (tid & 3) * 8;
  const unsigned short* ga1 = ga0 + (size_t)64 * K;
  const unsigned short* gb0 = Bm + (size_t)(n0 + (tid >> 2)) * K + (tid & 3) * 8;
  const unsigned short* gb1 = gb0 + (size_t)64 * K;

  f32x4 acc[4][4] = {};

  for (int k0 = 0; k0 < K; k0 += 32) {
    __syncthreads();
    load_lds16(ga0 + k0, &As[tid * 8]);
    load_lds16(ga1 + k0, &As[2048 + tid * 8]);
    load_lds16(gb0 + k0, &Bs[tid * 8]);
    load_lds16(gb1 + k0, &Bs[2048 + tid * 8]);
    __syncthreads();
    bf16x8 af[4], bfr[4];
#pragma unroll
    for (int i = 0; i < 4; ++i)
      af[i] = *(const bf16x8*)&As[(wr * 64 + i * 16 + r) * 32 + g * 8];
#pragma unroll
    for (int i = 0; i < 4; ++i)
      bfr[i] = *(const bf16x8*)&Bs[(wc * 64 + i * 16 + r) * 32 + g * 8];
#pragma unroll
    for (int i = 0; i < 4; ++i)
#pragma unroll
      for (int j = 0; j < 4; ++j)
        acc[i][j] = mfma16(af[i], bfr[j], acc[i][j]);
  }

#pragma unroll
  for (int i = 0; i < 4; ++i) {
    const int row = m0 + wr * 64 + i * 16 + g * 4;
#pragma unroll
    for (int j = 0; j < 4; ++j) {
      const int col = n0 + wc * 64 + j * 16 + r;
      const float bb = bias[col];
#pragma unroll
      for (int e = 0; e < 4; ++e) {
        const float v = acc[i][j][e] + bb;
        if (OUT_F32) ((float*)Cv)[(size_t)(row + e) * N + col] = v;
        else ((unsigned short*)Cv)[(size_t)(row + e) * N + col] = f2b(v);
      }
    }
  }
}

// ---------------- flash attention (causal, MQA) ----------------
// Barrier-free: K/V fragments loaded directly from global (L2-resident, 2 MB
// total). Swapped QK^T, Cauchy-bound softmax (no reductions), ones-MFMA
// denominator, per-wave LDS P round-trip only (9 KB LDS).

__global__ __launch_bounds__(256)
void mqa_attn(const unsigned short* __restrict__ QKV,
              const unsigned short* __restrict__ Vt,
              const float* __restrict__ Kmax,
              unsigned short* __restrict__ Ob) {
  __shared__ unsigned short Pl[4][16 * 72];   // per-wave P [q][kv], stride 72

  const int tid  = threadIdx.x;
  const int lane = tid & 63;
  const int wv   = tid >> 6;
  const int g    = lane >> 4;
  const int c    = lane & 15;
  const int qt   = 31 - blockIdx.x;      // heavy blocks dispatch first
  const int bh   = blockIdx.y;
  const int b    = bh >> 4;
  const int h    = bh & 15;
  const int qrow0 = qt * 64 + wv * 16;

  unsigned short* pw = &Pl[wv][0];

  // Q fragments: lane holds Q[q=qrow0+c][d = kk*32 + g*8 + e]
  bf16x8 qf[4];
  {
    const unsigned short* qp =
        QKV + (size_t)(b * S_LEN + qrow0 + c) * NQKV + h * D_ + g * 8;
#pragma unroll
    for (int kk = 0; kk < 4; ++kk) qf[kk] = *(const bf16x8*)(qp + kk * 32);
  }

  // Cauchy-Schwarz bound (exp2 domain): m0 = sscale*||q||*max||k|| + 1
  const float sscale = 0.08838834764831845f * 1.4426950408889634f;  // scale*log2e
  float qn2 = 0.f;
#pragma unroll
  for (int kk = 0; kk < 4; ++kk)
#pragma unroll
    for (int e = 0; e < 8; ++e) {
      const float qv = b2f((unsigned short)qf[kk][e]);
      qn2 += qv * qv;
    }
  qn2 += __shfl_xor(qn2, 16);
  qn2 += __shfl_xor(qn2, 32);
  const float m0c = sqrtf(qn2) * sqrtf(Kmax[b]) * sscale + 1.0f;

  const char* kbc = (const char*)(QKV + (size_t)(b * S_LEN) * NQKV + 2048);
  const char* vbc = (const char*)(Vt + (size_t)b * D_ * S_LEN);

  f32x4 acc[8];
#pragma unroll
  for (int i = 0; i < 8; ++i) { acc[i][0]=0.f; acc[i][1]=0.f; acc[i][2]=0.f; acc[i][3]=0.f; }
  f32x4 accl = {0.f, 0.f, 0.f, 0.f};     // row sums (denominator)

  bf16x8 onesf;
#pragma unroll
  for (int e = 0; e < 8; ++e) onesf[e] = (short)0x3F80;  // bf16 1.0

  const int nt = qt + 1;                 // KV tiles of 64
  const int qloc = qrow0 + c;            // this lane's absolute q row

  // per-lane 32-bit byte offsets; kk / half folded into imm offset
  int koff[4];
#pragma unroll
  for (int m = 0; m < 4; ++m) koff[m] = (c + 16 * m) * (NQKV * 2) + g * 16;
  int voff[8];
#pragma unroll
  for (int nf = 0; nf < 8; ++nf) voff[nf] = (nf * 16 + c) * (S_LEN * 2) + g * 16;

  for (int t = 0; t < nt; ++t) {
    const int kv0 = t * 64;
    const bool lastT = (t == nt - 1);
    const int mmax = lastT ? wv : 3;     // diagonal tile: skip chunks m > wv

    // K fragments (kv row = c + 16m, d = kk*32 + g*8)
    bf16x8 kf[4][4];
#pragma unroll
    for (int kk = 0; kk < 4; ++kk) kf[0][kk] = *(const bf16x8*)(kbc + koff[0] + kk * 64);
    if (1 <= mmax)
#pragma unroll
      for (int kk = 0; kk < 4; ++kk) kf[1][kk] = *(const bf16x8*)(kbc + koff[1] + kk * 64);
    if (2 <= mmax)
#pragma unroll
      for (int kk = 0; kk < 4; ++kk) kf[2][kk] = *(const bf16x8*)(kbc + koff[2] + kk * 64);
    if (3 <= mmax)
#pragma unroll
      for (int kk = 0; kk < 4; ++kk) kf[3][kk] = *(const bf16x8*)(kbc + koff[3] + kk * 64);

    // Swapped QK^T: s_m = K_m * Q ; D[row=kv=16m+4g+r][col=q=c]
    f32x4 s0={0.f,0.f,0.f,0.f}, s1={0.f,0.f,0.f,0.f},
          s2={0.f,0.f,0.f,0.f}, s3={0.f,0.f,0.f,0.f};
#pragma unroll
    for (int kk = 0; kk < 4; ++kk) {
      s0 = mfma16(kf[0][kk], qf[kk], s0);
      if (1 <= mmax) s1 = mfma16(kf[1][kk], qf[kk], s1);
      if (2 <= mmax) s2 = mfma16(kf[2][kk], qf[kk], s2);
      if (3 <= mmax) s3 = mfma16(kf[3][kk], qf[kk], s3);
    }

    // V fragments (d = nf*16 + c, kv = half*32 + g*8) -- issued to overlap softmax
    const bool doUp = !(lastT && wv < 2);
    bf16x8 vf0[8], vf1[8];
#pragma unroll
    for (int nf = 0; nf < 8; ++nf) vf0[nf] = *(const bf16x8*)(vbc + voff[nf]);
    if (doUp)
#pragma unroll
      for (int nf = 0; nf < 8; ++nf) vf1[nf] = *(const bf16x8*)(vbc + voff[nf] + 64);

    // p = exp2(s*sscale - m0) ; packed b64 write P[q=c][kv=16m+4g+r]
#define DOP(mi, sv)                                                            \
    {                                                                          \
      s16x4 pk;                                                                \
      _Pragma("unroll")                                                        \
      for (int r = 0; r < 4; ++r) {                                            \
        float a = sv[r] * sscale - m0c;                                        \
        if (lastT) {                                                           \
          const int kva = kv0 + 16 * mi + 4 * g + r;                           \
          if (kva > qloc) a = -__builtin_inff();                               \
        }                                                                      \
        pk[r] = (short)f2b(__builtin_amdgcn_exp2f(a));                         \
      }                                                                        \
      *(s16x4*)((char*)pw + c * 144 + mi * 32 + g * 8) = pk;                   \
    }
    DOP(0, s0) DOP(1, s1) DOP(2, s2) DOP(3, s3)
#undef DOP

    asm volatile("s_waitcnt lgkmcnt(0)" ::: "memory");
    __builtin_amdgcn_sched_barrier(0);
    const bf16x8 pf0 = *(const bf16x8*)&pw[c * 72 + g * 8];
    const bf16x8 pf1 = *(const bf16x8*)&pw[c * 72 + 32 + g * 8];

    // denominator: accl[r] = sum_kv P[q=4g+r][kv]  (ones-MFMA)
    accl = mfma16(pf0, onesf, accl);
    accl = mfma16(pf1, onesf, accl);

    // PV: acc[nf] += P(16x64) * V(64x16 per nf); D[row=q=4g+r][col=d=c]
#pragma unroll
    for (int nf = 0; nf < 8; ++nf) acc[nf] = mfma16(pf0, vf0[nf], acc[nf]);
    if (doUp)
#pragma unroll
      for (int nf = 0; nf < 8; ++nf) acc[nf] = mfma16(pf1, vf1[nf], acc[nf]);

    // advance tile offsets
#pragma unroll
    for (int m = 0; m < 4; ++m) koff[m] += 64 * (NQKV * 2);
#pragma unroll
    for (int nf = 0; nf < 8; ++nf) voff[nf] += 128;
  }

  // epilogue: normalize, store bf16 [4096][2048]
  unsigned short* op = Ob + (size_t)(b * S_LEN + qrow0 + 4 * g) * HID_ + h * D_ + c;
#pragma unroll
  for (int j = 0; j < 4; ++j) {
    const float inv = 1.0f / accl[j];
#pragma unroll
    for (int nf = 0; nf < 8; ++nf)
      op[(size_t)j * HID_ + nf * 16] = f2b(acc[nf][j] * inv);
  }
}

// ---------------- launcher ----------------

extern "C" void kernel_launch(void* const* d_in, const int* in_sizes, int n_in,
                              void* d_out, int out_size, void* d_ws, size_t ws_size,
                              hipStream_t stream) {
  (void)in_sizes; (void)n_in; (void)out_size; (void)ws_size;
  const float* x  = (const float*)d_in[0];
  const float* Wq = (const float*)d_in[2];
  const float* bq = (const float*)d_in[3];
  const float* Wk = (const float*)d_in[4];
  const float* bk = (const float*)d_in[5];
  const float* Wv = (const float*)d_in[6];
  const float* bv = (const float*)d_in[7];
  const float* Wo = (const float*)d_in[8];
  const float* bo = (const float*)d_in[9];
  float* out = (float*)d_out;

  char* p = (char*)d_ws;
  unsigned short* xb   = (unsigned short*)p;  p += (size_t)4096 * 2048 * 2;
  unsigned short* Wcat = (unsigned short*)p;  p += (size_t)2304 * 2048 * 2;
  float*          bcat = (float*)p;           p += 16384;
  unsigned short* Wob  = (unsigned short*)p;  p += (size_t)2048 * 2048 * 2;
  unsigned short* QKV  = (unsigned short*)p;  p += (size_t)4096 * 2304 * 2;
  unsigned short* Vt   = (unsigned short*)p;  p += (size_t)2 * 128 * 2048 * 2;
  float*          Kmax = (float*)p;           p += 64;
  unsigned short* Ob   = xb;  // xb dead after gemm1

  cast_f32_bf16_k<<<8192, 256, 0, stream>>>(x, xb, 2097152);
  build_wcat_k<<<4608, 256, 0, stream>>>(Wq, Wk, Wv, bq, bk, bv, Wcat, bcat, Kmax);
  cast_f32_bf16_k<<<4096, 256, 0, stream>>>(Wo, Wob, 1048576);
  gemm_nt<0><<<dim3(18, 32), 256, 0, stream>>>(xb, Wcat, bcat, QKV, 4096, NQKV, 2048);
  transpose_v<<<dim3(32, 2), 256, 0, stream>>>(QKV, Vt);
  kmax_k<<<16, 256, 0, stream>>>(QKV, Kmax);
  mqa_attn<<<dim3(32, 32), 256, 0, stream>>>(QKV, Vt, Kmax, Ob);
  gemm_nt<1><<<dim3(16, 32), 256, 0, stream>>>(Ob, Wob, bo, out, 4096, 2048, 2048);
}

// Round 5
// 234.165 us; speedup vs baseline: 2.5428x; 2.5428x over previous
//
#include <hip/hip_runtime.h>

// MQA: B=2, S=2048, HID=2048, H=16, D=128 (single KV head), causal.
// Pipeline: cast -> fused QKV NT-GEMM (bf16 MFMA) -> V transpose -> kmax ->
//           flash attention (8 waves, 256 q-rows/block, complementary causal
//           pairing, dbuf swizzled LDS KV, Cauchy-bound softmax) -> out GEMM.

#define S_LEN 2048
#define HID_  2048
#define D_    128
#define NQKV  2304   // 2048 Q + 128 K + 128 V columns

typedef __attribute__((ext_vector_type(8))) short bf16x8;
typedef __attribute__((ext_vector_type(4))) short s16x4;
typedef __attribute__((ext_vector_type(4))) float f32x4;

__device__ __forceinline__ unsigned short f2b(float f) {
  union { float f; unsigned int u; } a; a.f = f;
  unsigned int u = a.u;
  return (unsigned short)((u + 0x7fffu + ((u >> 16) & 1u)) >> 16);  // RNE
}

__device__ __forceinline__ float b2f(unsigned short s) {
  union { unsigned int u; float f; } a; a.u = ((unsigned int)s) << 16;
  return a.f;
}

__device__ __forceinline__ void load_lds16(const void* g, void* l) {
  __builtin_amdgcn_global_load_lds(
      (const __attribute__((address_space(1))) void*)g,
      (__attribute__((address_space(3))) void*)l, 16, 0, 0);
}

__device__ __forceinline__ f32x4 mfma16(bf16x8 a, bf16x8 b, f32x4 c) {
  return __builtin_amdgcn_mfma_f32_16x16x32_bf16(a, b, c, 0, 0, 0);
}

// ---------------- casts / packing ----------------

__global__ void cast_f32_bf16_k(const float* __restrict__ in,
                                unsigned short* __restrict__ out, int n4) {
  const int idx = blockIdx.x * 256 + threadIdx.x;
  if (idx < n4) {
    const float4 v = ((const float4*)in)[idx];
    ushort4 o;
    o.x = f2b(v.x); o.y = f2b(v.y); o.z = f2b(v.z); o.w = f2b(v.w);
    ((ushort4*)out)[idx] = o;
  }
}

__global__ void build_wcat_k(const float* __restrict__ Wq,
                             const float* __restrict__ Wk,
                             const float* __restrict__ Wv,
                             const float* __restrict__ bq,
                             const float* __restrict__ bk,
                             const float* __restrict__ bv,
                             unsigned short* __restrict__ Wcat,
                             float* __restrict__ bcat,
                             float* __restrict__ Kmax) {
  const int idx = blockIdx.x * 256 + threadIdx.x;
  const int i = idx * 4;
  const int row = i >> 11;
  const int col = i & 2047;
  const float* src;
  if (row < 2048)      src = Wq + (size_t)row * 2048 + col;
  else if (row < 2176) src = Wk + (size_t)(row - 2048) * 2048 + col;
  else                 src = Wv + (size_t)(row - 2176) * 2048 + col;
  const float4 v = *(const float4*)src;
  ushort4 o;
  o.x = f2b(v.x); o.y = f2b(v.y); o.z = f2b(v.z); o.w = f2b(v.w);
  *(ushort4*)(Wcat + i) = o;
  if (idx < NQKV)
    bcat[idx] = (idx < 2048) ? bq[idx] : (idx < 2176) ? bk[idx - 2048] : bv[idx - 2176];
  if (idx < 2) Kmax[idx] = 0.f;   // re-init every launch (runs before kmax_k)
}

// Vt[b][d][s] = QKV[b*S+s][2176+d] -- LDS-tiled transpose
__global__ __launch_bounds__(256)
void transpose_v(const unsigned short* __restrict__ QKV,
                 unsigned short* __restrict__ Vt) {
  __shared__ unsigned short tile[64][136];
  const int tid = threadIdx.x;
  const int s0  = blockIdx.x * 64;
  const int b   = blockIdx.y;
  const int row = tid >> 2;
  const int cb  = (tid & 3) * 32;
  const unsigned short* src = QKV + (size_t)(b * S_LEN + s0 + row) * NQKV + 2176 + cb;
#pragma unroll
  for (int i = 0; i < 4; ++i)
    *(bf16x8*)&tile[row][cb + i * 8] = *(const bf16x8*)(src + i * 8);
  __syncthreads();
  const int d  = tid >> 1;
  const int sc = (tid & 1) * 32;
  unsigned short* dst = Vt + ((size_t)b * D_ + d) * S_LEN + s0 + sc;
#pragma unroll
  for (int i = 0; i < 4; ++i) {
    bf16x8 vv;
#pragma unroll
    for (int e = 0; e < 8; ++e) vv[e] = tile[sc + i * 8 + e][d];
    *(bf16x8*)(dst + i * 8) = vv;
  }
}

// max_s ||k[b,s]||^2 -> Kmax[b] (as float bits via atomicMax on uint)
__global__ __launch_bounds__(256)
void kmax_k(const unsigned short* __restrict__ QKV, float* __restrict__ Kmax) {
  __shared__ float red[256];
  const int tid = threadIdx.x;
  const int b = blockIdx.x >> 3;
  const int s = (blockIdx.x & 7) * 256 + tid;
  const unsigned short* kp = QKV + (size_t)(b * S_LEN + s) * NQKV + 2048;
  float sum = 0.f;
#pragma unroll
  for (int i = 0; i < 16; ++i) {
    bf16x8 v = *(const bf16x8*)(kp + i * 8);
#pragma unroll
    for (int e = 0; e < 8; ++e) { const float f = b2f((unsigned short)v[e]); sum += f * f; }
  }
  red[tid] = sum;
  __syncthreads();
  for (int off = 128; off > 0; off >>= 1) {
    if (tid < off) red[tid] = fmaxf(red[tid], red[tid + off]);
    __syncthreads();
  }
  if (tid == 0) atomicMax((unsigned int*)(Kmax + b), __float_as_uint(red[0]));
}

// ---------------- NT GEMM (m97 structure, unchanged) ----------------

template <int OUT_F32>
__global__ __launch_bounds__(256)
void gemm_nt(const unsigned short* __restrict__ A,
             const unsigned short* __restrict__ Bm,
             const float* __restrict__ bias,
             void* __restrict__ Cv,
             int M, int N, int K) {
  __shared__ unsigned short As[128 * 32];
  __shared__ unsigned short Bs[128 * 32];
  const int tid  = threadIdx.x;
  const int lane = tid & 63;
  const int wv   = tid >> 6;
  const int wr   = wv >> 1, wc = wv & 1;
  const int g    = lane >> 4, r = lane & 15;
  const int m0   = blockIdx.y * 128;
  const int n0   = blockIdx.x * 128;

  const unsigned short* ga0 = A  + (size_t)(m0 + (tid >> 2)) * K + (tid & 3) * 8;
  const unsigned short* ga1 = ga0 + (size_t)64 * K;
  const unsigned short* gb0 = Bm + (size_t)(n0 + (tid >> 2)) * K + (tid & 3) * 8;
  const unsigned short* gb1 = gb0 + (size_t)64 * K;

  f32x4 acc[4][4] = {};

  for (int k0 = 0; k0 < K; k0 += 32) {
    __syncthreads();
    load_lds16(ga0 + k0, &As[tid * 8]);
    load_lds16(ga1 + k0, &As[2048 + tid * 8]);
    load_lds16(gb0 + k0, &Bs[tid * 8]);
    load_lds16(gb1 + k0, &Bs[2048 + tid * 8]);
    __syncthreads();
    bf16x8 af[4], bfr[4];
#pragma unroll
    for (int i = 0; i < 4; ++i)
      af[i] = *(const bf16x8*)&As[(wr * 64 + i * 16 + r) * 32 + g * 8];
#pragma unroll
    for (int i = 0; i < 4; ++i)
      bfr[i] = *(const bf16x8*)&Bs[(wc * 64 + i * 16 + r) * 32 + g * 8];
#pragma unroll
    for (int i = 0; i < 4; ++i)
#pragma unroll
      for (int j = 0; j < 4; ++j)
        acc[i][j] = mfma16(af[i], bfr[j], acc[i][j]);
  }

#pragma unroll
  for (int i = 0; i < 4; ++i) {
    const int row = m0 + wr * 64 + i * 16 + g * 4;
#pragma unroll
    for (int j = 0; j < 4; ++j) {
      const int col = n0 + wc * 64 + j * 16 + r;
      const float bb = bias[col];
#pragma unroll
      for (int e = 0; e < 4; ++e) {
        const float v = acc[i][j][e] + bb;
        if (OUT_F32) ((float*)Cv)[(size_t)(row + e) * N + col] = v;
        else ((unsigned short*)Cv)[(size_t)(row + e) * N + col] = f2b(v);
      }
    }
  }
}

// ---------------- flash attention (causal, MQA) ----------------
// 8 waves x 32 q-rows (2 strips of 16 sharing K/V frags) = 256 q-rows/block.
// Waves 0-3: rows [128j,128j+128); waves 4-7: rows [2048-128(j+1),2048-128j)
// -> constant work per block; grid 8x32 = 256 blocks = 1/CU.
// KVBLK=64 double-buffered XOR-swizzled LDS; Cauchy-bound softmax; ones-MFMA
// denominator; always-on causal mask (chunk skips are wave-uniform).

__global__ __launch_bounds__(512, 2)
void mqa_attn(const unsigned short* __restrict__ QKV,
              const unsigned short* __restrict__ Vt,
              const float* __restrict__ Kmax,
              unsigned short* __restrict__ Ob) {
  __shared__ __align__(16) char Ks[2][64 * 256];    // [kv][d] 256B rows, swizzled
  __shared__ __align__(16) char Vs[2][128 * 128];   // [d][kv] 128B rows, swizzled
  __shared__ __align__(16) char Pl[8][2][2304];     // per wave/strip P [16q][72kv]

  const int tid  = threadIdx.x;
  const int lane = tid & 63;
  const int wv   = tid >> 6;           // 0..7
  const int g    = lane >> 4;
  const int c    = lane & 15;
  const int j    = blockIdx.x;         // 0..7
  const int bh   = blockIdx.y;
  const int b    = bh >> 4;
  const int h    = bh & 15;
  // complementary pairing: low half for waves 0-3, high half for waves 4-7
  const int qb   = (wv < 4) ? (128 * j + 32 * wv)
                            : (2048 - 128 * (j + 1) + 32 * (wv - 4));
  const int nt   = 32 - 2 * j;         // KV tiles of 64 (covers high half's need)

  char* pw0 = &Pl[wv][0][0];
  char* pw1 = &Pl[wv][1][0];

  // Q fragments per strip: lane holds Q[q=qb+16*st+c][d = kk*32 + g*8 + e]
  bf16x8 qf[2][4];
#pragma unroll
  for (int st = 0; st < 2; ++st) {
    const unsigned short* qp =
        QKV + (size_t)(b * S_LEN + qb + 16 * st + c) * NQKV + h * D_ + g * 8;
#pragma unroll
    for (int kk = 0; kk < 4; ++kk) qf[st][kk] = *(const bf16x8*)(qp + kk * 32);
  }

  // Cauchy-Schwarz bound per strip: m0 = sscale*||q||*max||k|| + 1 (exp2 dom)
  const float sscale = 0.08838834764831845f * 1.4426950408889634f;  // scale*log2e
  const float km = sqrtf(Kmax[b]);
  float m0c[2];
#pragma unroll
  for (int st = 0; st < 2; ++st) {
    float qn2 = 0.f;
#pragma unroll
    for (int kk = 0; kk < 4; ++kk)
#pragma unroll
      for (int e = 0; e < 8; ++e) {
        const float qv = b2f((unsigned short)qf[st][kk][e]);
        qn2 += qv * qv;
      }
    qn2 += __shfl_xor(qn2, 16);
    qn2 += __shfl_xor(qn2, 32);
    m0c[st] = sqrtf(qn2) * km * sscale + 1.0f;
  }

  const char* kbc = (const char*)(QKV + (size_t)(b * S_LEN) * NQKV + 2048);
  const char* vbc = (const char*)(Vt + (size_t)b * D_ * S_LEN);

  f32x4 acc[2][8];
#pragma unroll
  for (int st = 0; st < 2; ++st)
#pragma unroll
    for (int i = 0; i < 8; ++i) { acc[st][i][0]=0.f; acc[st][i][1]=0.f; acc[st][i][2]=0.f; acc[st][i][3]=0.f; }
  f32x4 accl[2];
#pragma unroll
  for (int st = 0; st < 2; ++st) { accl[st][0]=0.f; accl[st][1]=0.f; accl[st][2]=0.f; accl[st][3]=0.f; }

  bf16x8 onesf;
#pragma unroll
  for (int e = 0; e < 8; ++e) onesf[e] = (short)0x3F80;  // bf16 1.0

  const int xr = (c & 15 & 7) << 4;    // = (c&7)<<4

  // ---- staging: 1024 chunks K (64x256B) + 1024 chunks V (128x128B), 512 thr ----
#define STAGE(bufi, t)                                                         \
  {                                                                            \
    const int kv0_ = (t) * 64;                                                 \
    _Pragma("unroll")                                                          \
    for (int i_ = 0; i_ < 2; ++i_) {                                           \
      const int ch_ = tid + 512 * i_;                                          \
      const int kr_ = ch_ >> 4;                                                \
      const int kc_ = ((ch_ & 15) << 4) ^ ((kr_ & 7) << 4);                    \
      load_lds16(kbc + (size_t)(kv0_ + kr_) * (NQKV * 2) + kc_,                \
                 Ks[bufi] + ch_ * 16);                                         \
      const int vr_ = ch_ >> 3;                                                \
      const int vc_ = ((ch_ & 7) << 4) ^ ((vr_ & 7) << 4);                     \
      load_lds16(vbc + (size_t)vr_ * (S_LEN * 2) + kv0_ * 2 + vc_,             \
                 Vs[bufi] + ch_ * 16);                                         \
    }                                                                          \
  }

  STAGE(0, 0);
  int cur = 0;

  for (int t = 0; t < nt; ++t) {
    __syncthreads();                       // publishes buf[cur]
    if (t + 1 < nt) STAGE(cur ^ 1, t + 1); // prefetch overlaps compute

    const char* ksb = Ks[cur];
    const char* vsb = Vs[cur];
    const int kv0 = t * 64;
    const int rel0 = qb + 15 - kv0;        // strip0 coverage
    const int rel1 = qb + 31 - kv0;        // strip1 coverage (>= rel0)
    cur ^= 1;
    if (rel1 < 0) continue;                // wave fully past-diagonal: stage only

    // QK^T (swapped): sc[st][m] = K_m * Q_st ; D[row=kv=16m+4g+r][col=q=c]
    f32x4 sc[2][4];
#pragma unroll
    for (int st = 0; st < 2; ++st)
#pragma unroll
      for (int m = 0; m < 4; ++m) { sc[st][m][0]=0.f; sc[st][m][1]=0.f; sc[st][m][2]=0.f; sc[st][m][3]=0.f; }

    __builtin_amdgcn_s_setprio(1);
#pragma unroll
    for (int kk = 0; kk < 4; ++kk) {
      const int cb = (kk * 64 + g * 16) ^ xr;
      bf16x8 kfm[4];
#pragma unroll
      for (int m = 0; m < 4; ++m)
        if (16 * m <= rel1) kfm[m] = *(const bf16x8*)(ksb + c * 256 + m * 4096 + cb);
#pragma unroll
      for (int m = 0; m < 4; ++m) {
        if (16 * m <= rel0) sc[0][m] = mfma16(kfm[m], qf[0][kk], sc[0][m]);
        if (16 * m <= rel1) sc[1][m] = mfma16(kfm[m], qf[1][kk], sc[1][m]);
      }
    }
    __builtin_amdgcn_s_setprio(0);

    // V fragments lower half (kv 0..31) -- independent of softmax
    bf16x8 vf0[8];
#pragma unroll
    for (int nf = 0; nf < 8; ++nf)
      vf0[nf] = *(const bf16x8*)(vsb + (nf * 16 + c) * 128 + ((g * 16) ^ xr));

    // softmax: p = exp2(s*sscale - m0), always-on causal mask; P fully written
#pragma unroll
    for (int st = 0; st < 2; ++st) {
      if (rel0 >= 0 || st == 1) {          // strip active iff rel_st >= 0
        if (st == 0 && rel0 < 0) continue;
        char* pwS = st ? pw1 : pw0;
        const float m0s = m0c[st];
        const int qloc = qb + 16 * st + c;
#pragma unroll
        for (int mi = 0; mi < 4; ++mi) {
          s16x4 pk;
#pragma unroll
          for (int r = 0; r < 4; ++r) {
            const int kva = kv0 + 16 * mi + 4 * g + r;
            float a = sc[st][mi][r] * sscale - m0s;
            a = (kva <= qloc) ? a : -__builtin_inff();
            pk[r] = (short)f2b(__builtin_amdgcn_exp2f(a));
          }
          *(s16x4*)(pwS + c * 144 + mi * 32 + g * 8) = pk;
        }
      }
    }
    asm volatile("s_waitcnt lgkmcnt(0)" ::: "memory");
    __builtin_amdgcn_sched_barrier(0);

    // PV + denominator per strip; pf1 half only when kv0+32 in range
    __builtin_amdgcn_s_setprio(1);
#pragma unroll
    for (int st = 0; st < 2; ++st) {
      const int rels = st ? rel1 : rel0;
      if (rels < 0) continue;
      const char* pwS = st ? pw1 : pw0;
      const bf16x8 pf0 = *(const bf16x8*)(pwS + c * 144 + g * 16);
      accl[st] = mfma16(pf0, onesf, accl[st]);
#pragma unroll
      for (int nf = 0; nf < 8; ++nf) acc[st][nf] = mfma16(pf0, vf0[nf], acc[st][nf]);
      if (rels >= 32) {
        const bf16x8 pf1 = *(const bf16x8*)(pwS + c * 144 + 64 + g * 16);
        accl[st] = mfma16(pf1, onesf, accl[st]);
#pragma unroll
        for (int nf = 0; nf < 8; ++nf) {
          const bf16x8 v1 = *(const bf16x8*)(vsb + (nf * 16 + c) * 128 + ((64 + g * 16) ^ xr));
          acc[st][nf] = mfma16(pf1, v1, acc[st][nf]);
        }
      }
    }
    __builtin_amdgcn_s_setprio(0);
  }

  // epilogue: normalize, store bf16 [4096][2048]
#pragma unroll
  for (int st = 0; st < 2; ++st) {
    unsigned short* op =
        Ob + (size_t)(b * S_LEN + qb + 16 * st + 4 * g) * HID_ + h * D_ + c;
#pragma unroll
    for (int jj = 0; jj < 4; ++jj) {
      const float inv = 1.0f / accl[st][jj];
#pragma unroll
      for (int nf = 0; nf < 8; ++nf)
        op[(size_t)jj * HID_ + nf * 16] = f2b(acc[st][nf][jj] * inv);
    }
  }
#undef STAGE
}

// ---------------- launcher ----------------

extern "C" void kernel_launch(void* const* d_in, const int* in_sizes, int n_in,
                              void* d_out, int out_size, void* d_ws, size_t ws_size,
                              hipStream_t stream) {
  (void)in_sizes; (void)n_in; (void)out_size; (void)ws_size;
  const float* x  = (const float*)d_in[0];
  const float* Wq = (const float*)d_in[2];
  const float* bq = (const float*)d_in[3];
  const float* Wk = (const float*)d_in[4];
  const float* bk = (const float*)d_in[5];
  const float* Wv = (const float*)d_in[6];
  const float* bv = (const float*)d_in[7];
  const float* Wo = (const float*)d_in[8];
  const float* bo = (const float*)d_in[9];
  float* out = (float*)d_out;

  char* p = (char*)d_ws;
  unsigned short* xb   = (unsigned short*)p;  p += (size_t)4096 * 2048 * 2;
  unsigned short* Wcat = (unsigned short*)p;  p += (size_t)2304 * 2048 * 2;
  float*          bcat = (float*)p;           p += 16384;
  unsigned short* Wob  = (unsigned short*)p;  p += (size_t)2048 * 2048 * 2;
  unsigned short* QKV  = (unsigned short*)p;  p += (size_t)4096 * 2304 * 2;
  unsigned short* Vt   = (unsigned short*)p;  p += (size_t)2 * 128 * 2048 * 2;
  float*          Kmax = (float*)p;           p += 64;
  unsigned short* Ob   = xb;  // xb dead after gemm1

  cast_f32_bf16_k<<<8192, 256, 0, stream>>>(x, xb, 2097152);
  build_wcat_k<<<4608, 256, 0, stream>>>(Wq, Wk, Wv, bq, bk, bv, Wcat, bcat, Kmax);
  cast_f32_bf16_k<<<4096, 256, 0, stream>>>(Wo, Wob, 1048576);
  gemm_nt<0><<<dim3(18, 32), 256, 0, stream>>>(xb, Wcat, bcat, QKV, 4096, NQKV, 2048);
  transpose_v<<<dim3(32, 2), 256, 0, stream>>>(QKV, Vt);
  kmax_k<<<16, 256, 0, stream>>>(QKV, Kmax);
  mqa_attn<<<dim3(8, 32), 512, 0, stream>>>(QKV, Vt, Kmax, Ob);
  gemm_nt<1><<<dim3(16, 32), 256, 0, stream>>>(Ob, Wob, bo, out, 4096, 2048, 2048);
}